// Round 2
// baseline (1372.752 us; speedup 1.0000x reference)
//
#include <hip/hip_runtime.h>
#include <hip/hip_bf16.h>
#include <cstdio>
#include <cstdint>

// Problem constants (N=16, C=128, H=W=128 -> HW=16384, Cr=64, M=128)
#define HWD   16384
#define NBATCH 16
#define CDIM  128
#define CRD   64
#define MF    128

constexpr float K_AMP = 2.4494897427831781f;   // sqrt(6)
constexpr float DN    = 0.35355339059327379f;  // 64^-0.25
constexpr float RATIO = 0.088388347648318447f; // 128^-0.5
constexpr float EPSN  = 5e-5f;
constexpr float EPSK  = 1e-4f;
constexpr float RES   = 0.1f;

// ---- workspace layout (float offsets) ----
constexpr size_t OFF_QP    = 0;                                      // [N][M][HW]
constexpr size_t OFF_KP    = OFF_QP    + (size_t)NBATCH*MF*HWD;      // [N][M][HW] (kd then kp in-place)
constexpr size_t OFF_KDIAG = OFF_KP    + (size_t)NBATCH*MF*HWD;      // [N][HW]
constexpr size_t OFF_GPART = OFF_KDIAG + (size_t)NBATCH*HWD;         // [32][N][M][C]
constexpr size_t OFF_G     = OFF_GPART + (size_t)32*NBATCH*MF*CDIM;  // [N][M][C]
constexpr size_t OFF_CTX   = OFF_G     + (size_t)NBATCH*MF*CDIM;     // [N][M][C]
constexpr size_t OFF_KSUM  = OFF_CTX   + (size_t)NBATCH*MF*CDIM;     // [N][M]
constexpr size_t OFF_BMAX  = OFF_KSUM  + (size_t)NBATCH*MF;          // [1024]
constexpr size_t OFF_KMAX  = OFF_BMAX  + 1024;                       // [1] (+pad)
constexpr size_t WS_FLOATS = OFF_KMAX  + 256;

// per-token: linear (C->Cr) + bias, l2norm, * K_AMP * DN; returns scaled feature + diag
__device__ __forceinline__ void token_features(const float* __restrict__ xp,
                                               const float* __restrict__ wf,
                                               const float* __restrict__ bf,
                                               float qs[CRD], float& diag) {
  #pragma unroll
  for (int c = 0; c < CRD; c++) qs[c] = 0.f;
  for (int c2 = 0; c2 < CDIM; c2 += 8) {   // wf index uniform -> s_load
    float xv[8];
    #pragma unroll
    for (int u = 0; u < 8; u++) xv[u] = xp[(size_t)(c2 + u) * HWD];
    #pragma unroll
    for (int c = 0; c < CRD; c++) {
      float s = qs[c];
      #pragma unroll
      for (int u = 0; u < 8; u++) s = fmaf(wf[c * CDIM + c2 + u], xv[u], s);
      qs[c] = s;
    }
  }
  float ss = 0.f;
  #pragma unroll
  for (int c = 0; c < CRD; c++) { qs[c] += bf[c]; ss = fmaf(qs[c], qs[c], ss); }
  float nrm = sqrtf(ss);
  float scale = (K_AMP * DN) / fmaxf(nrm, EPSN);
  float dd = 0.f;
  #pragma unroll
  for (int c = 0; c < CRD; c++) { float q = qs[c] * scale; qs[c] = q; dd = fmaf(q, q, dd); }
  diag = 0.5f * dd;
}

__device__ __forceinline__ float dot64(const float* __restrict__ qs, const float* __restrict__ pr) {
  float s0 = 0.f, s1 = 0.f, s2 = 0.f, s3 = 0.f;
  #pragma unroll
  for (int d = 0; d < CRD; d += 4) {
    s0 = fmaf(qs[d + 0], pr[d + 0], s0);
    s1 = fmaf(qs[d + 1], pr[d + 1], s1);
    s2 = fmaf(qs[d + 2], pr[d + 2], s2);
    s3 = fmaf(qs[d + 3], pr[d + 3], s3);
  }
  return (s0 + s1) + (s2 + s3);
}

// q path: writes qp[N][M][HW]
__global__ __launch_bounds__(256) void k_qp(const float* __restrict__ x,
                                            const float* __restrict__ w1f, const float* __restrict__ b1f,
                                            const float* __restrict__ projf, float* __restrict__ qp) {
  int t = blockIdx.x * 256 + threadIdx.x;     // 262144 tokens
  int n = t >> 14, i = t & (HWD - 1);
  float qs[CRD]; float qdiag;
  token_features(x + (size_t)n * CDIM * HWD + i, w1f, b1f, qs, qdiag);
  float qmax = -3.0e38f;
  for (int m = 0; m < MF; m++) qmax = fmaxf(qmax, dot64(qs, projf + m * CRD));
  float* qpo = qp + (size_t)n * MF * HWD + i;
  for (int m = 0; m < MF; m++) {
    float s = dot64(qs, projf + m * CRD);     // deterministic recompute (same order as pass 1)
    qpo[(size_t)m * HWD] = RATIO * (__expf(s - qdiag - qmax) + EPSK);
  }
}

// k path: writes kd[N][M][HW] (pre-exp), kdiag[N][HW], per-block max
__global__ __launch_bounds__(256) void k_kd(const float* __restrict__ x,
                                            const float* __restrict__ w2f, const float* __restrict__ b2f_,
                                            const float* __restrict__ projf, float* __restrict__ kd,
                                            float* __restrict__ kdiag, float* __restrict__ bmax) {
  int t = blockIdx.x * 256 + threadIdx.x;
  int n = t >> 14, i = t & (HWD - 1);
  float ks[CRD]; float kdg;
  token_features(x + (size_t)n * CDIM * HWD + i, w2f, b2f_, ks, kdg);
  kdiag[t] = kdg;
  float lmax = -3.0e38f;
  float* kdo = kd + (size_t)n * MF * HWD + i;
  for (int m = 0; m < MF; m++) {
    float s = dot64(ks, projf + m * CRD);
    kdo[(size_t)m * HWD] = s;
    lmax = fmaxf(lmax, s);
  }
  __shared__ float red[256];
  red[threadIdx.x] = lmax;
  __syncthreads();
  for (int w = 128; w > 0; w >>= 1) {
    if (threadIdx.x < w) red[threadIdx.x] = fmaxf(red[threadIdx.x], red[threadIdx.x + w]);
    __syncthreads();
  }
  if (threadIdx.x == 0) bmax[blockIdx.x] = red[0];
}

__global__ void k_redmax(const float* __restrict__ bmax, float* __restrict__ kmaxp) {
  __shared__ float red[256];
  float v = -3.0e38f;
  #pragma unroll
  for (int u = 0; u < 4; u++) v = fmaxf(v, bmax[threadIdx.x + 256 * u]);
  red[threadIdx.x] = v;
  __syncthreads();
  for (int w = 128; w > 0; w >>= 1) {
    if (threadIdx.x < w) red[threadIdx.x] = fmaxf(red[threadIdx.x], red[threadIdx.x + w]);
    __syncthreads();
  }
  if (threadIdx.x == 0) kmaxp[0] = red[0];
}

// kd -> kp in place (global kmax), plus ksum[n][m]
__global__ __launch_bounds__(256) void k_kp(float* __restrict__ kp, const float* __restrict__ kdiag,
                                            const float* __restrict__ kmaxp, float* __restrict__ ksum) {
  int nm = blockIdx.x;                 // 2048 rows
  int n = nm >> 7;
  float kmax = kmaxp[0];
  float* row = kp + (size_t)nm * HWD;
  const float* kdg = kdiag + (size_t)n * HWD;
  float s = 0.f;
  for (int it = 0; it < HWD / 256; it++) {
    int i = it * 256 + threadIdx.x;
    float e = RATIO * (__expf(row[i] - kdg[i] - kmax) + EPSK);
    row[i] = e;
    s += e;
  }
  __shared__ float red[256];
  red[threadIdx.x] = s;
  __syncthreads();
  for (int w = 128; w > 0; w >>= 1) {
    if (threadIdx.x < w) red[threadIdx.x] += red[threadIdx.x + w];
    __syncthreads();
  }
  if (threadIdx.x == 0) ksum[nm] = red[0];
}

// G partials: G[m][c2] += sum_i kp[m][i] * x[c2][i]  (chunk of 512 tokens per block)
__global__ __launch_bounds__(256) void k_gpart(const float* __restrict__ x,
                                               const float* __restrict__ kp, float* __restrict__ gpart) {
  int s = blockIdx.x, n = blockIdx.y;  // grid (32,16)
  int i0 = s * 512;
  __shared__ float kpt[16 * 132];      // [j][m], pad 132
  __shared__ float xt [16 * 132];      // [j][c2]
  int tid = threadIdx.x;
  int tm = tid & 15, tc = tid >> 4;
  float acc[8][8];
  #pragma unroll
  for (int a = 0; a < 8; a++)
    #pragma unroll
    for (int b = 0; b < 8; b++) acc[a][b] = 0.f;
  for (int sub = 0; sub < 32; sub++) {
    int ii = i0 + sub * 16;
    __syncthreads();
    #pragma unroll
    for (int u = 0; u < 8; u++) {
      int q = tid + 256 * u;           // 0..2047
      int r = q >> 4, j = q & 15;
      kpt[j * 132 + r] = kp[((size_t)n * MF + r) * HWD + ii + j];
      xt [j * 132 + r] = x[((size_t)n * CDIM + r) * HWD + ii + j];
    }
    __syncthreads();
    #pragma unroll
    for (int j = 0; j < 16; j++) {
      float kv[8], xv[8];
      *(float4*)&kv[0] = *(const float4*)&kpt[j * 132 + tm * 8];
      *(float4*)&kv[4] = *(const float4*)&kpt[j * 132 + tm * 8 + 4];
      *(float4*)&xv[0] = *(const float4*)&xt [j * 132 + tc * 8];
      *(float4*)&xv[4] = *(const float4*)&xt [j * 132 + tc * 8 + 4];
      #pragma unroll
      for (int a = 0; a < 8; a++)
        #pragma unroll
        for (int b = 0; b < 8; b++)
          acc[a][b] = fmaf(kv[a], xv[b], acc[a][b]);
    }
  }
  float* gp = gpart + (((size_t)s * NBATCH + n) << 14);
  #pragma unroll
  for (int a = 0; a < 8; a++) {
    #pragma unroll
    for (int b = 0; b < 8; b += 4) {
      float4 v4 = make_float4(acc[a][b], acc[a][b + 1], acc[a][b + 2], acc[a][b + 3]);
      *(float4*)&gp[(tm * 8 + a) * CDIM + tc * 8 + b] = v4;
    }
  }
}

__global__ void k_gred(const float* __restrict__ gpart, float* __restrict__ G) {
  int t = blockIdx.x * 256 + threadIdx.x;   // 262144
  int n = t >> 14, r = t & 16383;
  float s = 0.f;
  #pragma unroll
  for (int sc = 0; sc < 32; sc++) s += gpart[(((size_t)sc * NBATCH + n) << 14) + r];
  G[((size_t)n << 14) + r] = s;
}

// ctx[n][m][c] = sum_c2 wa[c][c2]*G[n][m][c2] + ba[c]*ksum[n][m]
__global__ __launch_bounds__(256) void k_ctx(const float* __restrict__ G, const float* __restrict__ waf,
                                             const float* __restrict__ baf, const float* __restrict__ ksum,
                                             float* __restrict__ ctx) {
  int n = blockIdx.x;                  // 16 blocks
  int tm = threadIdx.x & 15, tc = threadIdx.x >> 4;
  const float* Gn = G + ((size_t)n << 14);
  float acc[8][8];
  #pragma unroll
  for (int a = 0; a < 8; a++)
    #pragma unroll
    for (int b = 0; b < 8; b++) acc[a][b] = 0.f;
  for (int c2 = 0; c2 < CDIM; c2 += 4) {
    float4 g4[8], w4[8];
    #pragma unroll
    for (int a = 0; a < 8; a++) g4[a] = *(const float4*)&Gn[(tm * 8 + a) * CDIM + c2];
    #pragma unroll
    for (int b = 0; b < 8; b++) w4[b] = *(const float4*)&waf[(tc * 8 + b) * CDIM + c2];
    #pragma unroll
    for (int a = 0; a < 8; a++)
      #pragma unroll
      for (int b = 0; b < 8; b++) {
        acc[a][b] = fmaf(g4[a].x, w4[b].x, acc[a][b]);
        acc[a][b] = fmaf(g4[a].y, w4[b].y, acc[a][b]);
        acc[a][b] = fmaf(g4[a].z, w4[b].z, acc[a][b]);
        acc[a][b] = fmaf(g4[a].w, w4[b].w, acc[a][b]);
      }
  }
  #pragma unroll
  for (int a = 0; a < 8; a++) {
    int m = tm * 8 + a;
    float km = ksum[n * MF + m];
    #pragma unroll
    for (int b = 0; b < 8; b++) {
      int c = tc * 8 + b;
      ctx[((size_t)n * MF + m) * CDIM + c] = acc[a][b] + baf[c] * km;
    }
  }
}

// out[n][c][i] = 0.1 * d_inv[i] * sum_m ctx[n][m][c] * qp[n][m][i]; d_inv fused
__global__ __launch_bounds__(256) void k_out(const float* __restrict__ qp, const float* __restrict__ ctx,
                                             const float* __restrict__ ksum, float* __restrict__ out) {
  int n = blockIdx.y;
  int i0 = blockIdx.x * 64;            // grid (256,16)
  int tid = threadIdx.x;
  __shared__ float ksl[MF];
  __shared__ float dinv[64];
  __shared__ float ctxt[16 * 132];     // [mm][c]
  __shared__ float qpt [16 * 68];      // [mm][i]
  if (tid < MF) ksl[tid] = ksum[n * MF + tid];
  __syncthreads();
  if (tid < 64) {
    int i = i0 + tid;
    const float* qpn = qp + (size_t)n * MF * HWD + i;
    float s0 = 0.f, s1 = 0.f, s2 = 0.f, s3 = 0.f;
    for (int m = 0; m < MF; m += 4) {
      s0 = fmaf(qpn[(size_t)(m + 0) * HWD], ksl[m + 0], s0);
      s1 = fmaf(qpn[(size_t)(m + 1) * HWD], ksl[m + 1], s1);
      s2 = fmaf(qpn[(size_t)(m + 2) * HWD], ksl[m + 2], s2);
      s3 = fmaf(qpn[(size_t)(m + 3) * HWD], ksl[m + 3], s3);
    }
    dinv[tid] = RES / ((s0 + s1) + (s2 + s3));
  }
  int tc = tid & 15, ti = tid >> 4;
  float acc[8][4];
  #pragma unroll
  for (int a = 0; a < 8; a++)
    #pragma unroll
    for (int b = 0; b < 4; b++) acc[a][b] = 0.f;
  for (int mt = 0; mt < MF; mt += 16) {
    __syncthreads();                   // first one also publishes dinv
    #pragma unroll
    for (int u = 0; u < 8; u++) {
      int q = tid + 256 * u;           // 0..2047
      int mm = q >> 7, cc = q & 127;
      ctxt[mm * 132 + cc] = ctx[((size_t)n * MF + mt + mm) * CDIM + cc];
    }
    #pragma unroll
    for (int u = 0; u < 4; u++) {
      int q = tid + 256 * u;           // 0..1023
      int mm = q >> 6, jj = q & 63;
      qpt[mm * 68 + jj] = qp[((size_t)n * MF + mt + mm) * HWD + i0 + jj];
    }
    __syncthreads();
    #pragma unroll
    for (int mm = 0; mm < 16; mm++) {
      float q4[4], c8[8];
      *(float4*)&q4[0] = *(const float4*)&qpt [mm * 68 + ti * 4];
      *(float4*)&c8[0] = *(const float4*)&ctxt[mm * 132 + tc * 8];
      *(float4*)&c8[4] = *(const float4*)&ctxt[mm * 132 + tc * 8 + 4];
      #pragma unroll
      for (int a = 0; a < 8; a++)
        #pragma unroll
        for (int b = 0; b < 4; b++)
          acc[a][b] = fmaf(c8[a], q4[b], acc[a][b]);
    }
  }
  #pragma unroll
  for (int a = 0; a < 8; a++) {
    int c = tc * 8 + a;
    float4 v4;
    v4.x = acc[a][0] * dinv[ti * 4 + 0];
    v4.y = acc[a][1] * dinv[ti * 4 + 1];
    v4.z = acc[a][2] * dinv[ti * 4 + 2];
    v4.w = acc[a][3] * dinv[ti * 4 + 3];
    *(float4*)&out[((size_t)n * CDIM + c) * HWD + i0 + ti * 4] = v4;
  }
}

extern "C" void kernel_launch(void* const* d_in, const int* in_sizes, int n_in,
                              void* d_out, int out_size, void* d_ws, size_t ws_size,
                              hipStream_t stream) {
  (void)in_sizes; (void)n_in; (void)out_size;
  const float* x    = (const float*)d_in[0];
  const float* w1   = (const float*)d_in[1];
  const float* b1   = (const float*)d_in[2];
  const float* w2   = (const float*)d_in[3];
  const float* b2   = (const float*)d_in[4];
  const float* wa   = (const float*)d_in[5];
  const float* ba   = (const float*)d_in[6];
  const float* proj = (const float*)d_in[7];
  float* ws = (float*)d_ws;
  float* out = (float*)d_out;

  if (ws_size < WS_FLOATS * sizeof(float)) {
    fprintf(stderr, "ENLCA: workspace too small: need %zu bytes, have %zu\n",
            WS_FLOATS * sizeof(float), ws_size);
  }

  k_qp<<<1024, 256, 0, stream>>>(x, w1, b1, proj, ws + OFF_QP);
  k_kd<<<1024, 256, 0, stream>>>(x, w2, b2, proj, ws + OFF_KP, ws + OFF_KDIAG, ws + OFF_BMAX);
  k_redmax<<<1, 256, 0, stream>>>(ws + OFF_BMAX, ws + OFF_KMAX);
  k_kp<<<2048, 256, 0, stream>>>(ws + OFF_KP, ws + OFF_KDIAG, ws + OFF_KMAX, ws + OFF_KSUM);
  k_gpart<<<dim3(32, 16), 256, 0, stream>>>(x, ws + OFF_KP, ws + OFF_GPART);
  k_gred<<<1024, 256, 0, stream>>>(ws + OFF_GPART, ws + OFF_G);
  k_ctx<<<16, 256, 0, stream>>>(ws + OFF_G, wa, ba, ws + OFF_KSUM, ws + OFF_CTX);
  k_out<<<dim3(256, 16), 256, 0, stream>>>(ws + OFF_QP, ws + OFF_CTX, ws + OFF_KSUM, out);
}

// Round 3
// 516.511 us; speedup vs baseline: 2.6577x; 2.6577x over previous
//
#include <hip/hip_runtime.h>
#include <hip/hip_bf16.h>
#include <cstdio>
#include <cstdint>

// N=16, C=128, HW=16384, Cr=64, M=128
#define HWD 16384
#define NB  16
#define CD  128
#define CR  64
#define MF  128

constexpr float K_AMP = 2.4494897427831781f;   // sqrt(6)
constexpr float DN    = 0.35355339059327379f;  // 64^-0.25
constexpr float RATIO = 0.088388347648318447f; // 128^-0.5
constexpr float EPSN  = 5e-5f;
constexpr float EPSK  = 1e-4f;
constexpr float RES   = 0.1f;
constexpr float DIAG  = 0.375f;  // ||q||^2=6 after l2norm => qdiag = 0.5*6*dn^2 exactly

typedef __attribute__((ext_vector_type(4))) float f32x4;
typedef __attribute__((ext_vector_type(8))) short s16x8;

__device__ __forceinline__ short f2bf(float f) {
  __hip_bfloat16 h = __float2bfloat16(f);
  short s; __builtin_memcpy(&s, &h, 2); return s;
}
__device__ __forceinline__ float bf2f_s(short s) {
  __hip_bfloat16 h; __builtin_memcpy(&h, &s, 2); return __bfloat162float(h);
}
__device__ __forceinline__ f32x4 mfma16(s16x8 a, s16x8 b, f32x4 c) {
  return __builtin_amdgcn_mfma_f32_16x16x32_bf16(a, b, c, 0, 0, 0);
}

// ---- workspace layout (float offsets) ----
constexpr size_t OFF_QP   = 0;                          // bf16 [N][HW][M] -> 16.78M float slots
constexpr size_t OFF_KD   = OFF_QP   + 16777216;        // fp32 [N][HW][M]
constexpr size_t OFF_KP   = OFF_KD   + 33554432;        // bf16 [N][HW][M]
constexpr size_t OFF_GP   = OFF_KP   + 16777216;        // fp32 [32][N][M][C]
constexpr size_t OFF_G    = OFF_GP   + 8388608;         // fp32 [N][M][C]
constexpr size_t OFF_CTXB = OFF_G    + 262144;          // bf16 [N][C][M]
constexpr size_t OFF_KSUM = OFF_CTXB + 131072;          // fp32 [N][M]
constexpr size_t OFF_BMAX = OFF_KSUM + 2048;            // fp32 [2048]
constexpr size_t OFF_KMAX = OFF_BMAX + 2048;            // fp32 [8]
constexpr size_t OFF_W1B  = OFF_KMAX + 8;               // bf16 [64][128]
constexpr size_t OFF_W2B  = OFF_W1B  + 4096;
constexpr size_t OFF_PB   = OFF_W2B  + 4096;            // bf16 [128][64]
constexpr size_t WS_FLOATS = OFF_PB  + 4096;

// ---- weights -> bf16 ----
__global__ void k_prep(const float* __restrict__ w1, const float* __restrict__ w2,
                       const float* __restrict__ proj,
                       short* __restrict__ w1b, short* __restrict__ w2b, short* __restrict__ pb) {
  int t = blockIdx.x * 256 + threadIdx.x;   // 8192 threads; all three are 8192 elems
  w1b[t] = f2bf(w1[t]);
  w2b[t] = f2bf(w2[t]);
  pb[t]  = f2bf(proj[t]);
}

// ---- fused feature path: X->W·X->l2norm->·P^T->(Q: max+exp->qp bf16 | K: kd fp32 + block max)
template<bool IS_Q>
__global__ __launch_bounds__(256) void k_qk(const float* __restrict__ x,
                                            const short* __restrict__ wb,
                                            const float* __restrict__ bias,
                                            const short* __restrict__ pb,
                                            short* __restrict__ qp,     // IS_Q
                                            float* __restrict__ kd,     // !IS_Q
                                            float* __restrict__ bmax) { // !IS_Q
  const int n = blockIdx.y, i0 = blockIdx.x * 128;
  const int tid = threadIdx.x, lane = tid & 63, w = tid >> 6;
  const int l15 = lane & 15, q4 = lane >> 4;
  __shared__ short Xt[128 * 136];  // [i][c]
  __shared__ short Qt[128 * 72];   // [i][cr]
  __shared__ float bsh[64];
  __shared__ float wred[4];
  if (tid < 64) bsh[tid] = bias[tid];
  // stage Xt[i][c] bf16 (transpose: 4 c per thread-read, same i)
  #pragma unroll
  for (int u = 0; u < 16; u++) {
    int id = u * 256 + tid;
    int i = id & 127, cg = id >> 7;            // cg 0..31
    const float* xp = x + ((size_t)(n * CD + cg * 4) * HWD + i0 + i);
    short4 pk;
    pk.x = f2bf(xp[0]); pk.y = f2bf(xp[HWD]);
    pk.z = f2bf(xp[2 * HWD]); pk.w = f2bf(xp[3 * HWD]);
    *(short4*)&Xt[i * 136 + cg * 4] = pk;
  }
  __syncthreads();

  // GEMM1: Q[c_out=64][i=128] = W·X ; wave w: all c_out x i in [w*32, w*32+32)
  f32x4 acc1[4][2];
  #pragma unroll
  for (int ct = 0; ct < 4; ct++)
    #pragma unroll
    for (int it = 0; it < 2; it++) acc1[ct][it] = {0.f, 0.f, 0.f, 0.f};
  #pragma unroll
  for (int ks = 0; ks < 4; ks++) {
    s16x8 bfr[2];
    #pragma unroll
    for (int it = 0; it < 2; it++)
      bfr[it] = *(const s16x8*)&Xt[(w * 32 + it * 16 + l15) * 136 + ks * 32 + q4 * 8];
    #pragma unroll
    for (int ct = 0; ct < 4; ct++) {
      s16x8 afr = *(const s16x8*)&wb[(ct * 16 + l15) * 128 + ks * 32 + q4 * 8];
      #pragma unroll
      for (int it = 0; it < 2; it++) acc1[ct][it] = mfma16(afr, bfr[it], acc1[ct][it]);
    }
  }
  // bias + l2norm (per token i = column): lane holds c = ct*16+q4*4+r, i = it*16+l15 (+w*32)
  float qv[4][2][4];
  float ss[2] = {0.f, 0.f};
  #pragma unroll
  for (int ct = 0; ct < 4; ct++)
    #pragma unroll
    for (int it = 0; it < 2; it++)
      #pragma unroll
      for (int r = 0; r < 4; r++) {
        float v = acc1[ct][it][r] + bsh[ct * 16 + q4 * 4 + r];
        qv[ct][it][r] = v;
        ss[it] = fmaf(v, v, ss[it]);
      }
  #pragma unroll
  for (int it = 0; it < 2; it++) {
    ss[it] += __shfl_xor(ss[it], 16);
    ss[it] += __shfl_xor(ss[it], 32);
  }
  float scale[2];
  #pragma unroll
  for (int it = 0; it < 2; it++)
    scale[it] = (K_AMP * DN) / fmaxf(sqrtf(ss[it]), EPSN);
  // write Qt[i][cr] bf16 (4 consecutive cr packed)
  #pragma unroll
  for (int it = 0; it < 2; it++)
    #pragma unroll
    for (int ct = 0; ct < 4; ct++) {
      short4 pk;
      pk.x = f2bf(qv[ct][it][0] * scale[it]);
      pk.y = f2bf(qv[ct][it][1] * scale[it]);
      pk.z = f2bf(qv[ct][it][2] * scale[it]);
      pk.w = f2bf(qv[ct][it][3] * scale[it]);
      *(short4*)&Qt[(w * 32 + it * 16 + l15) * 72 + ct * 16 + q4 * 4] = pk;
    }
  __syncthreads();

  // GEMM2: QD[i=128][m=128] = Q' · P^T ; wave w: i in [w*32,+32) x all m
  f32x4 acc2[8][2];
  #pragma unroll
  for (int mt = 0; mt < 8; mt++)
    #pragma unroll
    for (int it = 0; it < 2; it++) acc2[mt][it] = {0.f, 0.f, 0.f, 0.f};
  #pragma unroll
  for (int ks = 0; ks < 2; ks++) {
    s16x8 afr[2];
    #pragma unroll
    for (int it = 0; it < 2; it++)
      afr[it] = *(const s16x8*)&Qt[(w * 32 + it * 16 + l15) * 72 + ks * 32 + q4 * 8];
    #pragma unroll
    for (int mt = 0; mt < 8; mt++) {
      s16x8 bfr = *(const s16x8*)&pb[(mt * 16 + l15) * 64 + ks * 32 + q4 * 8];
      #pragma unroll
      for (int it = 0; it < 2; it++) acc2[mt][it] = mfma16(afr[it], bfr, acc2[mt][it]);
    }
  }
  // D-tile: i = i0 + w*32 + it*16 + q4*4 + r ; m = mt*16 + l15
  if (IS_Q) {
    #pragma unroll
    for (int it = 0; it < 2; it++)
      #pragma unroll
      for (int r = 0; r < 4; r++) {
        float mx = -3.0e38f;
        #pragma unroll
        for (int mt = 0; mt < 8; mt++) mx = fmaxf(mx, acc2[mt][it][r]);
        mx = fmaxf(mx, __shfl_xor(mx, 1));
        mx = fmaxf(mx, __shfl_xor(mx, 2));
        mx = fmaxf(mx, __shfl_xor(mx, 4));
        mx = fmaxf(mx, __shfl_xor(mx, 8));
        int i = i0 + w * 32 + it * 16 + q4 * 4 + r;
        #pragma unroll
        for (int mt = 0; mt < 8; mt++) {
          float e = RATIO * (__expf(acc2[mt][it][r] - DIAG - mx) + EPSK);
          qp[((size_t)n * HWD + i) * MF + mt * 16 + l15] = f2bf(e);
        }
      }
  } else {
    float mx = -3.0e38f;
    #pragma unroll
    for (int it = 0; it < 2; it++)
      #pragma unroll
      for (int r = 0; r < 4; r++) {
        int i = i0 + w * 32 + it * 16 + q4 * 4 + r;
        #pragma unroll
        for (int mt = 0; mt < 8; mt++) {
          float v = acc2[mt][it][r];
          kd[((size_t)n * HWD + i) * MF + mt * 16 + l15] = v;
          mx = fmaxf(mx, v);
        }
      }
    #pragma unroll
    for (int d = 1; d < 64; d <<= 1) mx = fmaxf(mx, __shfl_xor(mx, d));
    if (lane == 0) wred[w] = mx;
    __syncthreads();
    if (tid == 0)
      bmax[blockIdx.y * 128 + blockIdx.x] =
          fmaxf(fmaxf(wred[0], wred[1]), fmaxf(wred[2], wred[3]));
  }
}

__global__ void k_redmax(const float* __restrict__ bmax, float* __restrict__ kmax,
                         float* __restrict__ ksum) {
  __shared__ float red[256];
  int t = threadIdx.x;
  float v = -3.0e38f;
  #pragma unroll
  for (int u = 0; u < 8; u++) {
    v = fmaxf(v, bmax[t + 256 * u]);
    ksum[t + 256 * u] = 0.f;   // zero ksum for k_kp2 atomics
  }
  red[t] = v;
  __syncthreads();
  for (int s = 128; s > 0; s >>= 1) {
    if (t < s) red[t] = fmaxf(red[t], red[t + s]);
    __syncthreads();
  }
  if (t == 0) kmax[0] = red[0];
}

// kd -> kp bf16 [n][i][m], ksum via atomics
__global__ __launch_bounds__(256) void k_kp2(const float* __restrict__ kd,
                                             const float* __restrict__ kmaxp,
                                             short* __restrict__ kp,
                                             float* __restrict__ ksum) {
  const int n = blockIdx.y, i0 = blockIdx.x * 128, t = threadIdx.x;
  const float km = kmaxp[0] + DIAG;
  const int m4 = (t & 31) * 4, irow = t >> 5;
  float p0 = 0.f, p1 = 0.f, p2 = 0.f, p3 = 0.f;
  #pragma unroll
  for (int u = 0; u < 16; u++) {
    int i = i0 + irow + 8 * u;
    const float4 v = *(const float4*)(kd + ((size_t)n * HWD + i) * MF + m4);
    float e0 = RATIO * (__expf(v.x - km) + EPSK);
    float e1 = RATIO * (__expf(v.y - km) + EPSK);
    float e2 = RATIO * (__expf(v.z - km) + EPSK);
    float e3 = RATIO * (__expf(v.w - km) + EPSK);
    p0 += e0; p1 += e1; p2 += e2; p3 += e3;
    short4 pk; pk.x = f2bf(e0); pk.y = f2bf(e1); pk.z = f2bf(e2); pk.w = f2bf(e3);
    *(short4*)&kp[((size_t)n * HWD + i) * MF + m4] = pk;
  }
  __shared__ float part[8 * 128];
  *(float4*)&part[irow * 128 + m4] = make_float4(p0, p1, p2, p3);
  __syncthreads();
  if (t < 128) {
    float s = 0.f;
    #pragma unroll
    for (int r = 0; r < 8; r++) s += part[r * 128 + t];
    atomicAdd(&ksum[n * MF + t], s);
  }
}

// G partials: Gp[slab][n][m][c] = sum_{i in slab} kp[i][m] * x[c][i]  (K=512/block)
__global__ __launch_bounds__(256) void k_g(const float* __restrict__ x,
                                           const short* __restrict__ kp,
                                           float* __restrict__ gp) {
  const int slab = blockIdx.x, n = blockIdx.y;
  const int t = threadIdx.x, lane = t & 63, w = t >> 6;
  const int l15 = lane & 15, q4 = lane >> 4;
  __shared__ short kl[64 * 136];   // [i][m]
  __shared__ short xl[128 * 72];   // [c][i]
  f32x4 acc[2][8];
  #pragma unroll
  for (int mt = 0; mt < 2; mt++)
    #pragma unroll
    for (int ct = 0; ct < 8; ct++) acc[mt][ct] = {0.f, 0.f, 0.f, 0.f};
  for (int ch = 0; ch < 8; ch++) {
    int ib = slab * 512 + ch * 64;
    __syncthreads();
    #pragma unroll
    for (int u = 0; u < 4; u++) {                   // kp chunk [64 i][128 m]
      int id = u * 256 + t, ii = id >> 4, m8 = (id & 15) * 8;
      *(s16x8*)&kl[ii * 136 + m8] =
          *(const s16x8*)&kp[((size_t)n * HWD + ib + ii) * MF + m8];
    }
    #pragma unroll
    for (int u = 0; u < 8; u++) {                   // x chunk [128 c][64 i]
      int id = u * 256 + t, c = id >> 4, i4 = (id & 15) * 4;
      const float4 v = *(const float4*)(x + ((size_t)n * CD + c) * HWD + ib + i4);
      short4 pk; pk.x = f2bf(v.x); pk.y = f2bf(v.y); pk.z = f2bf(v.z); pk.w = f2bf(v.w);
      *(short4*)&xl[c * 72 + i4] = pk;
    }
    __syncthreads();
    #pragma unroll
    for (int ks = 0; ks < 2; ks++) {
      s16x8 afr[2];
      #pragma unroll
      for (int mt = 0; mt < 2; mt++) {              // transpose-read kp: A[m][k=i]
        int m = w * 32 + mt * 16 + l15;
        short tmp[8];
        #pragma unroll
        for (int j = 0; j < 8; j++) tmp[j] = kl[(ks * 32 + q4 * 8 + j) * 136 + m];
        afr[mt] = *(s16x8*)tmp;
      }
      #pragma unroll
      for (int ct = 0; ct < 8; ct++) {
        s16x8 bfr = *(const s16x8*)&xl[(ct * 16 + l15) * 72 + ks * 32 + q4 * 8];
        #pragma unroll
        for (int mt = 0; mt < 2; mt++) acc[mt][ct] = mfma16(afr[mt], bfr, acc[mt][ct]);
      }
    }
  }
  float* g = gp + (((size_t)slab * NB + n) << 14);
  #pragma unroll
  for (int mt = 0; mt < 2; mt++)
    #pragma unroll
    for (int ct = 0; ct < 8; ct++)
      #pragma unroll
      for (int r = 0; r < 4; r++)
        g[(w * 32 + mt * 16 + q4 * 4 + r) * CD + ct * 16 + l15] = acc[mt][ct][r];
}

__global__ void k_gred(const float* __restrict__ gp, float* __restrict__ G) {
  int t = blockIdx.x * 256 + threadIdx.x;   // 262144
  int n = t >> 14, r = t & 16383;
  float s = 0.f;
  #pragma unroll
  for (int sc = 0; sc < 32; sc++) s += gp[(((size_t)sc * NB + n) << 14) + r];
  G[((size_t)n << 14) + r] = s;
}

// ctx[m][c] = sum_c2 wa[c][c2]*G[m][c2] + ba[c]*ksum[m]; writes ctx^T bf16 [c][m]
__global__ __launch_bounds__(256) void k_ctx(const float* __restrict__ G,
                                             const float* __restrict__ wa,
                                             const float* __restrict__ ba,
                                             const float* __restrict__ ksum,
                                             short* __restrict__ ctxb) {
  int n = blockIdx.x;
  int tm = threadIdx.x & 15, tc = threadIdx.x >> 4;
  const float* Gn = G + ((size_t)n << 14);
  float acc[8][8];
  #pragma unroll
  for (int a = 0; a < 8; a++)
    #pragma unroll
    for (int b = 0; b < 8; b++) acc[a][b] = 0.f;
  for (int c2 = 0; c2 < CD; c2 += 4) {
    float4 g4[8], w4[8];
    #pragma unroll
    for (int a = 0; a < 8; a++) g4[a] = *(const float4*)&Gn[(tm * 8 + a) * CD + c2];
    #pragma unroll
    for (int b = 0; b < 8; b++) w4[b] = *(const float4*)&wa[(tc * 8 + b) * CD + c2];
    #pragma unroll
    for (int a = 0; a < 8; a++)
      #pragma unroll
      for (int b = 0; b < 8; b++) {
        acc[a][b] = fmaf(g4[a].x, w4[b].x, acc[a][b]);
        acc[a][b] = fmaf(g4[a].y, w4[b].y, acc[a][b]);
        acc[a][b] = fmaf(g4[a].z, w4[b].z, acc[a][b]);
        acc[a][b] = fmaf(g4[a].w, w4[b].w, acc[a][b]);
      }
  }
  #pragma unroll
  for (int a = 0; a < 8; a++) {
    int m = tm * 8 + a;
    float km = ksum[n * MF + m];
    #pragma unroll
    for (int b = 0; b < 8; b++) {
      int c = tc * 8 + b;
      ctxb[((size_t)n * CD + c) * MF + m] = f2bf(acc[a][b] + ba[c] * km);
    }
  }
}

// out[c][i] = dinv[i] * sum_m ctx^T[c][m] * qp[i][m] ; dinv = RES / (qp·ksum)
__global__ __launch_bounds__(256) void k_out(const short* __restrict__ qp,
                                             const short* __restrict__ ctxb,
                                             const float* __restrict__ ksum,
                                             float* __restrict__ out) {
  const int n = blockIdx.y, i0 = blockIdx.x * 128;
  const int t = threadIdx.x, lane = t & 63, w = t >> 6;
  const int l15 = lane & 15, q4 = lane >> 4;
  __shared__ short qt[128 * 136];  // [i][m]
  __shared__ float ksl[128];
  __shared__ float dinv[128];
  if (t < 128) ksl[t] = ksum[n * MF + t];
  #pragma unroll
  for (int u = 0; u < 8; u++) {
    int id = u * 256 + t, i = id >> 4, m8 = (id & 15) * 8;
    *(s16x8*)&qt[i * 136 + m8] =
        *(const s16x8*)&qp[((size_t)n * HWD + i0 + i) * MF + m8];
  }
  __syncthreads();
  if (t < 128) {
    float s = 0.f;
    #pragma unroll
    for (int mb = 0; mb < 16; mb++) {
      s16x8 v = *(const s16x8*)&qt[t * 136 + mb * 8];
      #pragma unroll
      for (int j = 0; j < 8; j++) s = fmaf(bf2f_s(v[j]), ksl[mb * 8 + j], s);
    }
    dinv[t] = RES / s;
  }
  f32x4 acc[8][2];
  #pragma unroll
  for (int it = 0; it < 8; it++)
    #pragma unroll
    for (int ct = 0; ct < 2; ct++) acc[it][ct] = {0.f, 0.f, 0.f, 0.f};
  #pragma unroll
  for (int ks = 0; ks < 4; ks++) {
    s16x8 afr[2];
    #pragma unroll
    for (int ct = 0; ct < 2; ct++)
      afr[ct] = *(const s16x8*)&ctxb[((size_t)n * CD + w * 32 + ct * 16 + l15) * MF +
                                     ks * 32 + q4 * 8];
    #pragma unroll
    for (int it = 0; it < 8; it++) {
      s16x8 bfr = *(const s16x8*)&qt[(it * 16 + l15) * 136 + ks * 32 + q4 * 8];
      #pragma unroll
      for (int ct = 0; ct < 2; ct++) acc[it][ct] = mfma16(afr[ct], bfr, acc[it][ct]);
    }
  }
  __syncthreads();  // dinv ready
  #pragma unroll
  for (int it = 0; it < 8; it++) {
    float dv = dinv[it * 16 + l15];
    #pragma unroll
    for (int ct = 0; ct < 2; ct++)
      #pragma unroll
      for (int r = 0; r < 4; r++)
        out[((size_t)n * CD + w * 32 + ct * 16 + q4 * 4 + r) * HWD + i0 + it * 16 + l15] =
            acc[it][ct][r] * dv;
  }
}

extern "C" void kernel_launch(void* const* d_in, const int* in_sizes, int n_in,
                              void* d_out, int out_size, void* d_ws, size_t ws_size,
                              hipStream_t stream) {
  (void)in_sizes; (void)n_in; (void)out_size;
  const float* x    = (const float*)d_in[0];
  const float* w1   = (const float*)d_in[1];
  const float* b1   = (const float*)d_in[2];
  const float* w2   = (const float*)d_in[3];
  const float* b2   = (const float*)d_in[4];
  const float* wa   = (const float*)d_in[5];
  const float* ba   = (const float*)d_in[6];
  const float* proj = (const float*)d_in[7];
  float* ws  = (float*)d_ws;
  float* out = (float*)d_out;

  if (ws_size < WS_FLOATS * sizeof(float)) {
    fprintf(stderr, "ENLCA: workspace too small: need %zu, have %zu\n",
            WS_FLOATS * sizeof(float), ws_size);
  }

  short* qpB   = (short*)(ws + OFF_QP);
  float* kdF   = ws + OFF_KD;
  short* kpB   = (short*)(ws + OFF_KP);
  float* gpF   = ws + OFF_GP;
  float* GF    = ws + OFF_G;
  short* ctxB  = (short*)(ws + OFF_CTXB);
  float* ksumF = ws + OFF_KSUM;
  float* bmaxF = ws + OFF_BMAX;
  float* kmaxF = ws + OFF_KMAX;
  short* w1B   = (short*)(ws + OFF_W1B);
  short* w2B   = (short*)(ws + OFF_W2B);
  short* pB    = (short*)(ws + OFF_PB);

  k_prep<<<32, 256, 0, stream>>>(w1, w2, proj, w1B, w2B, pB);
  k_qk<true><<<dim3(128, 16), 256, 0, stream>>>(x, w1B, b1, pB, qpB, nullptr, nullptr);
  k_qk<false><<<dim3(128, 16), 256, 0, stream>>>(x, w2B, b2, pB, nullptr, kdF, bmaxF);
  k_redmax<<<1, 256, 0, stream>>>(bmaxF, kmaxF, ksumF);
  k_kp2<<<dim3(128, 16), 256, 0, stream>>>(kdF, kmaxF, kpB, ksumF);
  k_g<<<dim3(32, 16), 256, 0, stream>>>(x, kpB, gpF);
  k_gred<<<1024, 256, 0, stream>>>(gpF, GF);
  k_ctx<<<16, 256, 0, stream>>>(GF, wa, ba, ksumF, ctxB);
  k_out<<<dim3(128, 16), 256, 0, stream>>>(qpB, ctxB, ksumF, out);
}